// Round 5
// baseline (848.850 us; speedup 1.0000x reference)
//
#include <hip/hip_runtime.h>
#include <hip/hip_fp16.h>
#include <cstdint>
#include <cstddef>

// Problem dims
#define B_    64
#define T_    256
#define D_    512
#define U_    500
#define UP_   512            // padded units
#define NCOL_ 2048           // 4*UP_
#define K_    1024           // D_ + UP_

typedef _Float16 f16x8 __attribute__((ext_vector_type(8)));
typedef float    f32x4 __attribute__((ext_vector_type(4)));

// ---- workspace layout (bytes) ----
#define OFF_X   0ull                         // x fp16: 64*256*512*2        = 16777216
#define OFF_W   16777216ull                  // Wcomb fp16: 2*2048*1024*2   = 8388608
#define OFF_B   25165824ull                  // bcomb f32: 2*2048*4         = 16384
#define OFF_H   25182208ull                  // h_buf fp16: 8*2*8192*2      = 262144

// ---- LDS layout (bytes) ----
#define LW  0                // W slice: 64 cols * 2048B (col-major, swizzled) 128KB
#define LX  131072           // x tile: 16 rows * 1024B (swizzled) 16KB (single buf)
#define LZ  147456           // z exchange: 4*272*4 = 4352B
#define LDS_BYTES 151808

#define TAGMASK 0x0003000300030003ull

#define GLD_LDS16(g, l) \
  __builtin_amdgcn_global_load_lds((const __attribute__((address_space(1))) void*)(g), \
                                   (__attribute__((address_space(3))) void*)(l), 16, 0, 0)

// ============================ prep kernels ============================

__global__ void prep_x(const float* __restrict__ x, _Float16* __restrict__ xf) {
  size_t base = ((size_t)blockIdx.x * 256 + threadIdx.x) * 8;
  const float4* p = (const float4*)(x + base);
  float4 a = p[0], b = p[1];
  f16x8 v;
  v[0] = (_Float16)a.x; v[1] = (_Float16)a.y; v[2] = (_Float16)a.z; v[3] = (_Float16)a.w;
  v[4] = (_Float16)b.x; v[5] = (_Float16)b.y; v[6] = (_Float16)b.z; v[7] = (_Float16)b.w;
  *(f16x8*)(xf + base) = v;
}

__global__ void prep_w(const float* __restrict__ Wkf, const float* __restrict__ Wrf,
                       const float* __restrict__ Wkb, const float* __restrict__ Wrb,
                       const float* __restrict__ bf,  const float* __restrict__ bb,
                       _Float16* __restrict__ Wc, float* __restrict__ bcomb) {
  size_t gid = (size_t)blockIdx.x * 256 + threadIdx.x;
  int dir = (int)(gid >> 18);
  int rem = (int)(gid & 262143);
  int col = rem >> 7;
  int k0  = (rem & 127) << 3;
  const float* Wk = dir ? Wkb : Wkf;
  const float* Wr = dir ? Wrb : Wrf;
  int g = (col >> 4) & 3, du = col & 15, utc = col >> 6;
  int ug = utc * 16 + du;
  bool valid = (ug < U_);
  int c4 = g * U_ + ug;
  f16x8 out;
#pragma unroll
  for (int kk = 0; kk < 8; ++kk) {
    int k = k0 + kk;
    float v = 0.f;
    if (valid) {
      if (k < D_) v = Wk[(size_t)k * (4 * U_) + c4];
      else { int u = k - D_; if (u < U_) v = Wr[(size_t)u * (4 * U_) + c4]; }
    }
    out[kk] = (_Float16)v;
  }
  *(f16x8*)(Wc + ((size_t)dir * NCOL_ + col) * K_ + k0) = out;

  if (gid < 4096) {
    int d2 = (int)(gid >> 11), c2 = (int)(gid & 2047);
    int g2 = (c2 >> 4) & 3, du2 = c2 & 15, ut2 = c2 >> 6;
    int ug2 = ut2 * 16 + du2;
    const float* bs = d2 ? bb : bf;
    bcomb[gid] = (ug2 < U_) ? bs[g2 * U_ + ug2] : 0.f;
  }
}

// h_buf layout: [gi][parity][p=u>>4][row][u&15] fp16 with 2-bit step tags in-band.
// prep writes h0 into parity 0 with tag 0 (= step-0 expectation).
__global__ void prep_hb(const float* __restrict__ hf, const float* __restrict__ hb,
                        _Float16* __restrict__ hbuf) {
  int idx = blockIdx.x * 256 + threadIdx.x;    // < 65536
  int dir = idx >> 15;
  int rem = idx & 32767;
  int bt = rem >> 13, r = (rem >> 9) & 15, u = rem & 511;
  const float* h0 = dir ? hb : hf;
  float v = (u < U_) ? h0[(size_t)(bt * 16 + r) * U_ + u] : 0.f;
  int gi = dir * 4 + bt;
  union { _Float16 f; unsigned short s; } cv;
  cv.f = (_Float16)v;
  cv.s &= 0xFFFC;   // tag = 0
  ((unsigned short*)hbuf)[(size_t)(gi * 2 + 0) * 8192 + (u >> 4) * 256 + r * 16 + (u & 15)] = cv.s;
}

// ============================ persistent scan ============================
// 256 blocks (1/CU), 256 threads. Block = (dir, bt, ut): 16 rows x 16 units.
// Handoff: tagged-data poll. Producer packs 4 fp16 h (low 2 bits of each half
// = 2 bits of the 8-bit step tag) into one 8B agent-scope atomic store.
// Consumers poll their own MFMA A-fragment chunks until all tags match step t.
// Single IC round trip; no fences, counters, flags, or drains.
__global__ __launch_bounds__(256, 1) void lstm_scan(
    const _Float16* __restrict__ xf, const _Float16* __restrict__ Wc,
    const float* __restrict__ bc, const float* __restrict__ cf,
    const float* __restrict__ cb, _Float16* __restrict__ hbuf,
    float* __restrict__ y)
{
  extern __shared__ __align__(16) char lds[];
  const int tid  = threadIdx.x;
  const int lane = tid & 63;
  const int w    = tid >> 6;        // wave id == gate id (i,f,g,o)
  const int bid  = blockIdx.x;
  const int grp  = bid & 7;         // group -> same XCD under round-robin (perf only)
  const int dir  = grp >> 2;
  const int bt   = grp & 3;
  const int ut   = bid >> 3;

  // ---- prologue: W slice -> LDS (col-major, 16B-chunk XOR swizzle) ----
  {
    const int4* wsrc = (const int4*)(Wc + ((size_t)dir * NCOL_ + (size_t)ut * 64) * K_);
    for (int it = 0; it < 32; ++it) {
      int idx = it * 256 + tid;
      int j = idx >> 7, ch = idx & 127;
      int4 v = wsrc[j * 128 + ch];
      *(int4*)(lds + LW + (size_t)j * 2048 + ((ch ^ (j & 7)) << 4)) = v;
    }
  }
  const float bias = bc[dir * NCOL_ + ut * 64 + w * 16 + (lane & 15)];
  const int r0 = tid >> 4, du0 = tid & 15;
  const int ug0 = ut * 16 + du0;
  const float* cin = dir ? cb : cf;
  float c = (ug0 < U_) ? cin[(size_t)(bt * 16 + r0) * U_ + ug0] : 0.f;

  const int gi = dir * 4 + bt;
  _Float16* hb = hbuf + (size_t)gi * 2 * 8192;
  const int colj = w * 16 + (lane & 15);
  const int arow = lane & 15;
  const int kg   = lane >> 4;
  const char* wcol = lds + LW + (size_t)colj * 2048;
  const char* xrow = lds + LX + (size_t)arow * 1024;
  const int cswz = colj & 7, aswz = arow & 7;
  float* zw = (float*)(lds + LZ);

  // stage x[0] (wave w stages rows 4w..4w+3)
  {
    const int t_x0 = dir ? (T_ - 1) : 0;
    for (int rr = 0; rr < 4; ++rr) {
      int r = w * 4 + rr;
      const char* src = (const char*)(xf + ((size_t)(bt * 16 + r) * T_ + t_x0) * D_)
                        + ((lane ^ (r & 7)) << 4);
      GLD_LDS16(src, lds + LX + r * 1024);
    }
  }
  __syncthreads();   // W + x[0] resident

  // x-MFMA for t=0
  f32x4 ax0 = {0.f,0.f,0.f,0.f}, ax1 = {0.f,0.f,0.f,0.f};
#pragma unroll
  for (int ks = 0; ks < 16; ++ks) {
    int ch = ks * 4 + kg;
    f16x8 a = *(const f16x8*)(xrow + ((ch ^ aswz) << 4));
    f16x8 b = *(const f16x8*)(wcol + ((ch ^ cswz) << 4));
    if (ks & 1) ax1 = __builtin_amdgcn_mfma_f32_16x16x32_f16(a, b, ax1, 0, 0, 0);
    else        ax0 = __builtin_amdgcn_mfma_f32_16x16x32_f16(a, b, ax0, 0, 0, 0);
  }
  __syncthreads();   // all waves done reading x[0]

  // stage x[1]
  {
    const int t_x1 = dir ? (T_ - 2) : 1;
    for (int rr = 0; rr < 4; ++rr) {
      int r = w * 4 + rr;
      const char* src = (const char*)(xf + ((size_t)(bt * 16 + r) * T_ + t_x1) * D_)
                        + ((lane ^ (r & 7)) << 4);
      GLD_LDS16(src, lds + LX + r * 1024);
    }
  }

  for (int t = 0; t < T_; ++t) {
    const int t_x = dir ? (T_ - 1 - t) : t;

    // ---- poll tagged h fragments (input to step t, parity t&1, tag t&255) ----
    const unsigned long long* hr =
        (const unsigned long long*)(hb + (size_t)(t & 1) * 8192);
    unsigned tag = (unsigned)(t & 255);
    unsigned long long expect =
        (unsigned long long)(tag & 3)
      | ((unsigned long long)((tag >> 2) & 3) << 16)
      | ((unsigned long long)((tag >> 4) & 3) << 32)
      | ((unsigned long long)((tag >> 6) & 3) << 48);

    unsigned long long v[32];
    while (true) {
#pragma unroll
      for (int ks = 0; ks < 16; ++ks) {
        int ch = ks * 4 + kg;
        int bidx = (ch >> 1) * 64 + arow * 4 + (ch & 1) * 2;
        v[2*ks]   = __hip_atomic_load(hr + bidx,     __ATOMIC_RELAXED, __HIP_MEMORY_SCOPE_AGENT);
        v[2*ks+1] = __hip_atomic_load(hr + bidx + 1, __ATOMIC_RELAXED, __HIP_MEMORY_SCOPE_AGENT);
      }
      bool ok = true;
#pragma unroll
      for (int i = 0; i < 32; ++i) ok &= ((v[i] & TAGMASK) == expect);
      if (__all(ok)) break;
      __builtin_amdgcn_s_sleep(1);
    }

    // ---- h-part MFMAs (tag bits left in-band: <=3 ulp noise on h) ----
    f32x4 ah0 = {0.f,0.f,0.f,0.f}, ah1 = {0.f,0.f,0.f,0.f};
#pragma unroll
    for (int ks = 0; ks < 16; ++ks) {
      int ch = ks * 4 + kg;
      union { unsigned long long u[2]; f16x8 f; } tmp;
      tmp.u[0] = v[2*ks]; tmp.u[1] = v[2*ks+1];
      f16x8 b = *(const f16x8*)(wcol + (((64 + ch) ^ cswz) << 4));
      if (ks & 1) ah1 = __builtin_amdgcn_mfma_f32_16x16x32_f16(tmp.f, b, ah1, 0, 0, 0);
      else        ah0 = __builtin_amdgcn_mfma_f32_16x16x32_f16(tmp.f, b, ah0, 0, 0, 0);
    }

    // ---- z exchange through LDS (stride-17 rows) ----
    __syncthreads();
#pragma unroll
    for (int q = 0; q < 4; ++q) {
      float zv = ax0[q] + ax1[q] + ah0[q] + ah1[q] + bias;
      zw[w * 272 + (kg * 4 + q) * 17 + (lane & 15)] = zv;
    }
    __syncthreads();

    // ---- gate combine: thread -> (row r0, unit du0), c in register ----
    float h;
    {
      const float* zr = (const float*)(lds + LZ);
      int zb = r0 * 17 + du0;
      float zi = zr[zb], zf = zr[272 + zb], zg = zr[544 + zb], zo = zr[816 + zb];
      float ig = 1.f / (1.f + __expf(-zi));
      float fg = 1.f / (1.f + __expf(-zf));
      float e2 = __expf(2.f * zg);
      float gg = (e2 - 1.f) / (e2 + 1.f);
      float og = 1.f / (1.f + __expf(-zo));
      c = fg * c + ig * gg;
      float ec = __expf(2.f * c);
      float th = (ec - 1.f) / (ec + 1.f);
      h = og * th;
    }

    // ---- publish tagged h: 8B atomic store per 4 units (fire & forget) ----
    {
      unsigned ptag = (unsigned)((t + 1) & 255);
      union { _Float16 f; unsigned short s; } cv;
      cv.f = (_Float16)h;
      unsigned tagged = ((unsigned)cv.s & 0xFFFCu) | ((ptag >> (2 * (du0 & 3))) & 3u);
      unsigned pair = tagged | ((unsigned)__shfl_xor((int)tagged, 1, 64) << 16);
      unsigned other = (unsigned)__shfl_xor((int)pair, 2, 64);
      if ((du0 & 3) == 0) {
        unsigned long long u = (unsigned long long)pair | ((unsigned long long)other << 32);
        unsigned long long* hbw = (unsigned long long*)(hb + (size_t)((t + 1) & 1) * 8192);
        __hip_atomic_store(hbw + ut * 64 + r0 * 4 + (du0 >> 2), u,
                           __ATOMIC_RELAXED, __HIP_MEMORY_SCOPE_AGENT);
      }
    }

    // ---- x-MFMA for t+1 (x[t+1] resident; covers publish flight) ----
    if (t + 1 < T_) {
      f32x4 nx0 = {0.f,0.f,0.f,0.f}, nx1 = {0.f,0.f,0.f,0.f};
#pragma unroll
      for (int ks = 0; ks < 16; ++ks) {
        int ch = ks * 4 + kg;
        f16x8 a = *(const f16x8*)(xrow + ((ch ^ aswz) << 4));
        f16x8 b = *(const f16x8*)(wcol + ((ch ^ cswz) << 4));
        if (ks & 1) nx1 = __builtin_amdgcn_mfma_f32_16x16x32_f16(a, b, nx1, 0, 0, 0);
        else        nx0 = __builtin_amdgcn_mfma_f32_16x16x32_f16(a, b, nx0, 0, 0, 0);
      }
      ax0 = nx0; ax1 = nx1;
    }
    __syncthreads();   // all waves done reading x[t+1]

    // stage x[t+2]
    if (t + 2 < T_) {
      const int t_n = dir ? (T_ - 3 - t) : (t + 2);
      for (int rr = 0; rr < 4; ++rr) {
        int r = w * 4 + rr;
        const char* src = (const char*)(xf + ((size_t)(bt * 16 + r) * T_ + t_n) * D_)
                          + ((lane ^ (r & 7)) << 4);
        GLD_LDS16(src, lds + LX + r * 1024);
      }
    }

    // y store (off critical path)
    if (ug0 < U_)
      y[((size_t)(bt * 16 + r0) * T_ + t_x) * (2 * U_) + dir * U_ + ug0] = h;
  }
}

// ============================ launcher ============================
extern "C" void kernel_launch(void* const* d_in, const int* in_sizes, int n_in,
                              void* d_out, int out_size, void* d_ws, size_t ws_size,
                              hipStream_t stream) {
  (void)in_sizes; (void)n_in; (void)out_size; (void)ws_size;
  const float* x    = (const float*)d_in[0];
  const float* h_f  = (const float*)d_in[1];
  const float* c_f  = (const float*)d_in[2];
  const float* h_b  = (const float*)d_in[3];
  const float* c_b  = (const float*)d_in[4];
  const float* Wk_f = (const float*)d_in[5];
  const float* Wr_f = (const float*)d_in[6];
  const float* b_f  = (const float*)d_in[7];
  const float* Wk_b = (const float*)d_in[8];
  const float* Wr_b = (const float*)d_in[9];
  const float* b_b  = (const float*)d_in[10];

  char* ws = (char*)d_ws;
  _Float16* xf    = (_Float16*)(ws + OFF_X);
  _Float16* Wc    = (_Float16*)(ws + OFF_W);
  float*    bcomb = (float*)   (ws + OFF_B);
  _Float16* hbuf  = (_Float16*)(ws + OFF_H);
  float*    y     = (float*)d_out;

  prep_x<<<4096, 256, 0, stream>>>(x, xf);
  prep_w<<<2048, 256, 0, stream>>>(Wk_f, Wr_f, Wk_b, Wr_b, b_f, b_b, Wc, bcomb);
  prep_hb<<<256, 256, 0, stream>>>(h_f, h_b, hbuf);

  static bool attr_done = false;
  if (!attr_done) {
    (void)hipFuncSetAttribute((const void*)lstm_scan,
                              hipFuncAttributeMaxDynamicSharedMemorySize, LDS_BYTES);
    attr_done = true;
  }
  lstm_scan<<<256, 256, LDS_BYTES, stream>>>(xf, Wc, bcomb, c_f, c_b, hbuf, y);
}

// Round 6
// 482.933 us; speedup vs baseline: 1.7577x; 1.7577x over previous
//
#include <hip/hip_runtime.h>
#include <hip/hip_fp16.h>
#include <cstdint>
#include <cstddef>

// Problem dims
#define B_    64
#define T_    256
#define D_    512
#define U_    500
#define UP_   512            // padded units
#define NCOL_ 2048           // 4*UP_
#define K_    1024           // D_ + UP_

typedef _Float16 f16x8 __attribute__((ext_vector_type(8)));
typedef float    f32x4 __attribute__((ext_vector_type(4)));

// ---- workspace layout (bytes) ----
#define OFF_X   0ull                         // x fp16: 64*256*512*2        = 16777216
#define OFF_W   16777216ull                  // Wcomb fp16: 2*2048*1024*2   = 8388608
#define OFF_B   25165824ull                  // bcomb f32: 2*2048*4         = 16384
#define OFF_H   25182208ull                  // h_buf fp16: 8*2*8192*2      = 262144

// ---- LDS layout (bytes), static 52KB ----
#define LXA 0                // x tile buf0: 16 rows * 1024B (swizzled)
#define LXB 16384            // x tile buf1
#define LZP 32768            // z partials: 4 waves * 64 cols * 20 f32 = 20480B
#define LDS_BYTES 53248

#define TAGMASK 0x0003000300030003ull

#define GLD_LDS16(g, l) \
  __builtin_amdgcn_global_load_lds((const __attribute__((address_space(1))) void*)(g), \
                                   (__attribute__((address_space(3))) void*)(l), 16, 0, 0)

// ============================ prep kernels ============================

__global__ void prep_x(const float* __restrict__ x, _Float16* __restrict__ xf) {
  size_t base = ((size_t)blockIdx.x * 256 + threadIdx.x) * 8;
  const float4* p = (const float4*)(x + base);
  float4 a = p[0], b = p[1];
  f16x8 v;
  v[0] = (_Float16)a.x; v[1] = (_Float16)a.y; v[2] = (_Float16)a.z; v[3] = (_Float16)a.w;
  v[4] = (_Float16)b.x; v[5] = (_Float16)b.y; v[6] = (_Float16)b.z; v[7] = (_Float16)b.w;
  *(f16x8*)(xf + base) = v;
}

__global__ void prep_w(const float* __restrict__ Wkf, const float* __restrict__ Wrf,
                       const float* __restrict__ Wkb, const float* __restrict__ Wrb,
                       const float* __restrict__ bf,  const float* __restrict__ bb,
                       _Float16* __restrict__ Wc, float* __restrict__ bcomb) {
  size_t gid = (size_t)blockIdx.x * 256 + threadIdx.x;
  int dir = (int)(gid >> 18);
  int rem = (int)(gid & 262143);
  int col = rem >> 7;
  int k0  = (rem & 127) << 3;
  const float* Wk = dir ? Wkb : Wkf;
  const float* Wr = dir ? Wrb : Wrf;
  int g = (col >> 4) & 3, du = col & 15, utc = col >> 6;
  int ug = utc * 16 + du;
  bool valid = (ug < U_);
  int c4 = g * U_ + ug;
  f16x8 out;
#pragma unroll
  for (int kk = 0; kk < 8; ++kk) {
    int k = k0 + kk;
    float v = 0.f;
    if (valid) {
      if (k < D_) v = Wk[(size_t)k * (4 * U_) + c4];
      else { int u = k - D_; if (u < U_) v = Wr[(size_t)u * (4 * U_) + c4]; }
    }
    out[kk] = (_Float16)v;
  }
  *(f16x8*)(Wc + ((size_t)dir * NCOL_ + col) * K_ + k0) = out;

  if (gid < 4096) {
    int d2 = (int)(gid >> 11), c2 = (int)(gid & 2047);
    int g2 = (c2 >> 4) & 3, du2 = c2 & 15, ut2 = c2 >> 6;
    int ug2 = ut2 * 16 + du2;
    const float* bs = d2 ? bb : bf;
    bcomb[gid] = (ug2 < U_) ? bs[g2 * U_ + ug2] : 0.f;
  }
}

// h_buf layout: [gi][parity][p=u>>4][row][u&15] fp16, 2-bit step tags in-band.
__global__ void prep_hb(const float* __restrict__ hf, const float* __restrict__ hb,
                        _Float16* __restrict__ hbuf) {
  int idx = blockIdx.x * 256 + threadIdx.x;    // < 65536
  int dir = idx >> 15;
  int rem = idx & 32767;
  int bt = rem >> 13, r = (rem >> 9) & 15, u = rem & 511;
  const float* h0 = dir ? hb : hf;
  float v = (u < U_) ? h0[(size_t)(bt * 16 + r) * U_ + u] : 0.f;
  int gi = dir * 4 + bt;
  union { _Float16 f; unsigned short s; } cv;
  cv.f = (_Float16)v;
  cv.s &= 0xFFFC;   // tag = 0
  ((unsigned short*)hbuf)[(size_t)(gi * 2 + 0) * 8192 + (u >> 4) * 256 + r * 16 + (u & 15)] = cv.s;
}

// ============================ persistent scan ============================
// 256 blocks (1/CU), 256 threads. Block = (dir, bt, ut): 16 rows x 16 units.
// K-split waves: wave w owns K-slice [w*256, w*256+256) for ALL 64 cols.
// W B-fragments resident in VGPRs (no LDS W). h-waves (2,3) poll tagged h
// chunks straight into their MFMA A-fragments. Cross-wave K-reduction + gate
// through a small zp LDS buffer. 2 barriers/step.
__global__ __launch_bounds__(256, 1) void lstm_scan(
    const _Float16* __restrict__ xf, const _Float16* __restrict__ Wc,
    const float* __restrict__ bc, const float* __restrict__ cf,
    const float* __restrict__ cb, _Float16* __restrict__ hbuf,
    float* __restrict__ y)
{
  __shared__ __align__(16) char lds[LDS_BYTES];
  const int tid  = threadIdx.x;
  const int lane = tid & 63;
  const int w    = tid >> 6;        // wave id == K-slice id
  const int bid  = blockIdx.x;
  const int grp  = bid & 7;         // group -> same XCD under round-robin (perf only)
  const int dir  = grp >> 2;
  const int bt   = grp & 3;
  const int ut   = bid >> 3;

  const int c15  = lane & 15;       // B col-in-tile / A row
  const int kg   = lane >> 4;       // k-group
  const int arow = c15;

  // ---- B-fragments -> registers (32 x f16x8 = 128 VGPR) ----
  f16x8 breg[4][8];
  {
    const _Float16* wbase = Wc + ((size_t)dir * NCOL_ + (size_t)ut * 64) * K_ + w * 256;
#pragma unroll
    for (int ct = 0; ct < 4; ++ct)
#pragma unroll
      for (int ks = 0; ks < 8; ++ks)
        breg[ct][ks] = *(const f16x8*)(wbase + (size_t)(ct * 16 + c15) * K_ + ks * 32 + kg * 8);
  }

  const int r0 = tid >> 4, du0 = tid & 15;
  const int ug0 = ut * 16 + du0;
  float bg[4];
#pragma unroll
  for (int g = 0; g < 4; ++g) bg[g] = bc[dir * NCOL_ + ut * 64 + g * 16 + du0];
  const float* cin = dir ? cb : cf;
  float c = (ug0 < U_) ? cin[(size_t)(bt * 16 + r0) * U_ + ug0] : 0.f;

  const int gi = dir * 4 + bt;
  _Float16* hb = hbuf + (size_t)gi * 2 * 8192;

  // stage x[0] -> bufA, x[1] -> bufB (wave w stages rows 4w..4w+3)
#pragma unroll
  for (int tt = 0; tt < 2; ++tt) {
    const int t_x0 = dir ? (T_ - 1 - tt) : tt;
    char* dst = lds + (tt ? LXB : LXA);
    for (int rr = 0; rr < 4; ++rr) {
      int r = w * 4 + rr;
      const char* src = (const char*)(xf + ((size_t)(bt * 16 + r) * T_ + t_x0) * D_)
                        + ((lane ^ (r & 7)) << 4);
      GLD_LDS16(src, dst + r * 1024);
    }
  }
  __syncthreads();

  float* zpw = (float*)(lds + LZP) + w * 1280;   // this wave's partial area
  const float* zr = (const float*)(lds + LZP);

  for (int t = 0; t < T_; ++t) {
    const int t_x = dir ? (T_ - 1 - t) : t;

    f32x4 acc[4] = {{0.f,0.f,0.f,0.f},{0.f,0.f,0.f,0.f},{0.f,0.f,0.f,0.f},{0.f,0.f,0.f,0.f}};

    if (w >= 2) {
      // ---- h-waves: poll tagged h chunks (units (w-2)*256 .. +255) ----
      const unsigned long long* hr =
          (const unsigned long long*)(hb + (size_t)(t & 1) * 8192);
      unsigned tag = (unsigned)(t & 255);
      unsigned long long expect =
          (unsigned long long)(tag & 3)
        | ((unsigned long long)((tag >> 2) & 3) << 16)
        | ((unsigned long long)((tag >> 4) & 3) << 32)
        | ((unsigned long long)((tag >> 6) & 3) << 48);
      const int chb = (w - 2) * 32;

      unsigned long long v[16];
      while (true) {
#pragma unroll
        for (int ks = 0; ks < 8; ++ks) {
          int ch = chb + ks * 4 + kg;
          int bidx = (ch >> 1) * 64 + arow * 4 + (ch & 1) * 2;
          v[2*ks]   = __hip_atomic_load(hr + bidx,     __ATOMIC_RELAXED, __HIP_MEMORY_SCOPE_AGENT);
          v[2*ks+1] = __hip_atomic_load(hr + bidx + 1, __ATOMIC_RELAXED, __HIP_MEMORY_SCOPE_AGENT);
        }
        bool ok = true;
#pragma unroll
        for (int i = 0; i < 16; ++i) ok &= ((v[i] & TAGMASK) == expect);
        if (__all(ok)) break;
        __builtin_amdgcn_s_sleep(1);
      }
      // polled regs ARE the A-fragments (tag bits = <=3ulp noise)
#pragma unroll
      for (int ks = 0; ks < 8; ++ks) {
        union { unsigned long long u[2]; f16x8 f; } tmp;
        tmp.u[0] = v[2*ks]; tmp.u[1] = v[2*ks+1];
#pragma unroll
        for (int ct = 0; ct < 4; ++ct)
          acc[ct] = __builtin_amdgcn_mfma_f32_16x16x32_f16(tmp.f, breg[ct][ks], acc[ct], 0, 0, 0);
      }
    } else {
      // ---- x-waves: A-fragments from LDS x tile ----
      const char* xb = lds + ((t & 1) ? LXB : LXA);
#pragma unroll
      for (int ks = 0; ks < 8; ++ks) {
        int ch = w * 32 + ks * 4 + kg;
        f16x8 a = *(const f16x8*)(xb + arow * 1024 + ((ch ^ (arow & 7)) << 4));
#pragma unroll
        for (int ct = 0; ct < 4; ++ct)
          acc[ct] = __builtin_amdgcn_mfma_f32_16x16x32_f16(a, breg[ct][ks], acc[ct], 0, 0, 0);
      }
    }

    // ---- write K-partials: zp[w][col][row], row-stride 20 f32 ----
#pragma unroll
    for (int ct = 0; ct < 4; ++ct)
      *(f32x4*)(zpw + (ct * 16 + c15) * 20 + kg * 4) = acc[ct];
    __syncthreads();   // B1: all partials ready; x[t] reads done

    // stage x[t+2] -> buf[t&1] (issue early, drains by use at t+2)
    if (t + 2 < T_) {
      const int t_n = dir ? (T_ - 3 - t) : (t + 2);
      char* dst = lds + ((t & 1) ? LXB : LXA);
      for (int rr = 0; rr < 4; ++rr) {
        int r = w * 4 + rr;
        const char* src = (const char*)(xf + ((size_t)(bt * 16 + r) * T_ + t_n) * D_)
                          + ((lane ^ (r & 7)) << 4);
        GLD_LDS16(src, dst + r * 1024);
      }
    }

    // ---- gate combine: thread (r0, du0); 4-way K-reduction fused ----
    float h;
    {
      float z[4];
#pragma unroll
      for (int g = 0; g < 4; ++g) {
        int cb2 = (g * 16 + du0) * 20 + r0;
        z[g] = bg[g] + zr[cb2] + zr[1280 + cb2] + zr[2560 + cb2] + zr[3840 + cb2];
      }
      float ig = 1.f / (1.f + __expf(-z[0]));
      float fg = 1.f / (1.f + __expf(-z[1]));
      float e2 = __expf(2.f * z[2]);
      float gg = (e2 - 1.f) / (e2 + 1.f);
      float og = 1.f / (1.f + __expf(-z[3]));
      c = fg * c + ig * gg;
      float ec = __expf(2.f * c);
      float th = (ec - 1.f) / (ec + 1.f);
      h = og * th;
    }

    // ---- publish tagged h: 8B atomic store per 4 units ----
    {
      unsigned ptag = (unsigned)((t + 1) & 255);
      union { _Float16 f; unsigned short s; } cv;
      cv.f = (_Float16)h;
      unsigned tagged = ((unsigned)cv.s & 0xFFFCu) | ((ptag >> (2 * (du0 & 3))) & 3u);
      unsigned pair = tagged | ((unsigned)__shfl_xor((int)tagged, 1, 64) << 16);
      unsigned other = (unsigned)__shfl_xor((int)pair, 2, 64);
      if ((du0 & 3) == 0) {
        unsigned long long u = (unsigned long long)pair | ((unsigned long long)other << 32);
        unsigned long long* hbw = (unsigned long long*)(hb + (size_t)((t + 1) & 1) * 8192);
        __hip_atomic_store(hbw + ut * 64 + r0 * 4 + (du0 >> 2), u,
                           __ATOMIC_RELAXED, __HIP_MEMORY_SCOPE_AGENT);
      }
    }

    // y store (off critical path)
    if (ug0 < U_)
      y[((size_t)(bt * 16 + r0) * T_ + t_x) * (2 * U_) + dir * U_ + ug0] = h;

    __syncthreads();   // B2: zp reads done (next iter rewrites)
  }
}

// ============================ launcher ============================
extern "C" void kernel_launch(void* const* d_in, const int* in_sizes, int n_in,
                              void* d_out, int out_size, void* d_ws, size_t ws_size,
                              hipStream_t stream) {
  (void)in_sizes; (void)n_in; (void)out_size; (void)ws_size;
  const float* x    = (const float*)d_in[0];
  const float* h_f  = (const float*)d_in[1];
  const float* c_f  = (const float*)d_in[2];
  const float* h_b  = (const float*)d_in[3];
  const float* c_b  = (const float*)d_in[4];
  const float* Wk_f = (const float*)d_in[5];
  const float* Wr_f = (const float*)d_in[6];
  const float* b_f  = (const float*)d_in[7];
  const float* Wk_b = (const float*)d_in[8];
  const float* Wr_b = (const float*)d_in[9];
  const float* b_b  = (const float*)d_in[10];

  char* ws = (char*)d_ws;
  _Float16* xf    = (_Float16*)(ws + OFF_X);
  _Float16* Wc    = (_Float16*)(ws + OFF_W);
  float*    bcomb = (float*)   (ws + OFF_B);
  _Float16* hbuf  = (_Float16*)(ws + OFF_H);
  float*    y     = (float*)d_out;

  prep_x<<<4096, 256, 0, stream>>>(x, xf);
  prep_w<<<2048, 256, 0, stream>>>(Wk_f, Wr_f, Wk_b, Wr_b, b_f, b_b, Wc, bcomb);
  prep_hb<<<256, 256, 0, stream>>>(h_f, h_b, hbuf);

  lstm_scan<<<256, 256, 0, stream>>>(xf, Wc, bcomb, c_f, c_b, hbuf, y);
}